// Round 4
// baseline (252.443 us; speedup 1.0000x reference)
//
#include <hip/hip_runtime.h>

// Problem constants: B=2, T=2048, C=1024, H=16, HS=64
typedef unsigned short u16;
typedef unsigned int u32;
typedef __bf16 bf16x8 __attribute__((ext_vector_type(8)));
typedef float f32x4 __attribute__((ext_vector_type(4)));
typedef u16 u16x4 __attribute__((ext_vector_type(4)));
typedef u16 u16x8 __attribute__((ext_vector_type(8)));

__device__ __forceinline__ u16 f2bf(float f) {
  u32 u = __builtin_bit_cast(u32, f);
  u += 0x7fffu + ((u >> 16) & 1u);   // round-to-nearest-even
  return (u16)(u >> 16);
}

// pack two f32 -> two bf16 (round-half-up) in one u32; a in low half.
__device__ __forceinline__ u32 pk2(float a, float b) {
  u32 ua = __builtin_bit_cast(u32, a) + 0x8000u;
  u32 ub = __builtin_bit_cast(u32, b) + 0x8000u;
  return __builtin_amdgcn_perm(ub, ua, 0x07060302);  // {ub.hi16, ua.hi16}
}

__device__ __forceinline__ void gld16(const void* g, void* l) {
  __builtin_amdgcn_global_load_lds(
      (const __attribute__((address_space(1))) void*)g,
      (__attribute__((address_space(3))) void*)l, 16, 0, 0);
}

// ---------------- merged prep kernel (one launch) ----------------
__global__ __launch_bounds__(256) void k_prep(
    const float* __restrict__ x, u16* __restrict__ xb,
    const float* __restrict__ Wqkv, u16* __restrict__ Wqkvt,
    const float* __restrict__ Wproj, u16* __restrict__ Wpt,
    float2* __restrict__ rope) {
  __shared__ float tile[32][33];
  const int tid = threadIdx.x;
  int bx = blockIdx.x;
  if (bx < 4096) {
    int i = (bx * 256 + tid) * 4;
    float4 v = *(const float4*)(x + i);
    u16x4 o = { f2bf(v.x), f2bf(v.y), f2bf(v.z), f2bf(v.w) };
    *(u16x4*)(xb + i) = o;
    return;
  }
  bx -= 4096;
  const float* src; u16* dst; int R, Cc, bxx, byy;
  if (bx < 3072) {
    src = Wqkv; dst = Wqkvt; R = 1024; Cc = 3072; bxx = bx % 96; byy = bx / 96;
  } else if (bx < 4096) {
    int b = bx - 3072;
    src = Wproj; dst = Wpt; R = 1024; Cc = 1024; bxx = b % 32; byy = b / 32;
  } else {
    int i = (bx - 4096) * 256 + tid;  // 0..65535
    int t = i >> 5, d = i & 31;
    float theta = expf(-(float)d * 0.28782313662425575f);  // ln(10000)/32
    float ang = (float)t * theta;
    rope[i] = make_float2(cosf(ang), sinf(ang));
    return;
  }
  int xx = tid & 31, yy = tid >> 5;
  int c0 = bxx * 32, r0 = byy * 32;
  for (int i = 0; i < 4; ++i)
    tile[yy + 8 * i][xx] = src[(size_t)(r0 + yy + 8 * i) * Cc + c0 + xx];
  __syncthreads();
  for (int i = 0; i < 4; ++i)
    dst[(size_t)(c0 + yy + 8 * i) * R + r0 + xx] = f2bf(tile[xx][yy + 8 * i]);
}

// --------------- QKV GEMM + bias + RoPE + scatter ---------------
// Q is pre-scaled by 1/sqrt(HS)*log2(e) here so k_attn's softmax is a bare
// exp2 of the MFMA output.
__global__ __launch_bounds__(256, 4) void k_qkv(
    const u16* __restrict__ Xb,      // [4096][1024] bf16
    const u16* __restrict__ Wt,      // [3072][1024] bf16 (W_qkv^T)
    const float* __restrict__ bias,  // [3072]
    const float2* __restrict__ rope, // [2048][32]
    u16* __restrict__ Qg,            // [B,H,T,HS]  (scaled)
    u16* __restrict__ Kg,            // [B,H,T,HS]
    u16* __restrict__ Vt) {          // [B,H,HS,T]
  __shared__ alignas(16) u16 smem[18432];  // 36 KB: As|Bs in K-loop, Es after
  u16* As = smem;           // [128][64]
  u16* Bs = smem + 8192;    // [128][64]
  const int tid = threadIdx.x;
  const int lane = tid & 63, w = tid >> 6;
  const int quad = lane >> 4, l15 = lane & 15;
  const int m0 = blockIdx.y * 128, n0 = blockIdx.x * 128;
  const int wm = (w & 1) * 64, wn = (w >> 1) * 64;
  const int srow = lane >> 3, sj = lane & 7;
  const int sw = (sj ^ srow) * 8;   // swizzled source u16 offset
  const f32x4 vzero = {0.f, 0.f, 0.f, 0.f};

  f32x4 acc[4][4];  // [nt][mt] (swapped order)
  for (int i = 0; i < 4; ++i)
    for (int j = 0; j < 4; ++j) acc[i][j] = vzero;

  for (int kt = 0; kt < 1024; kt += 64) {
    __syncthreads();
    for (int i = 0; i < 4; ++i) {
      int row = w * 32 + i * 8;
      gld16(Xb + (size_t)(m0 + row + srow) * 1024 + kt + sw, &As[row * 64]);
      gld16(Wt + (size_t)(n0 + row + srow) * 1024 + kt + sw, &Bs[row * 64]);
    }
    __syncthreads();
    for (int ks = 0; ks < 2; ++ks) {
      const int cc = ((ks * 4 + quad) ^ (l15 & 7)) * 8;
      bf16x8 a[4], b[4];
      for (int mt = 0; mt < 4; ++mt)
        a[mt] = *(const bf16x8*)&As[(wm + mt * 16 + l15) * 64 + cc];
      for (int nt = 0; nt < 4; ++nt)
        b[nt] = *(const bf16x8*)&Bs[(wn + nt * 16 + l15) * 64 + cc];
      for (int nt = 0; nt < 4; ++nt)
        for (int mt = 0; mt < 4; ++mt)
          acc[nt][mt] = __builtin_amdgcn_mfma_f32_16x16x32_bf16(
              b[nt], a[mt], acc[nt][mt], 0, 0, 0);
    }
  }
  __syncthreads();  // all waves done reading As/Bs; safe to overwrite with Es

  // ---- stage into LDS (bias + RoPE applied), wave-uniform region per half
  const int half = w >> 1;
  const int nh = n0 + half * 64;             // 64-aligned -> single region
  const int region = (nh % 192) >> 6;        // 0=Q 1=K 2=V
  u16* Eh = smem + half * 9216;
  if (region < 2) {
    const float qsc = (region == 0) ? 0.18033688011112042f : 1.0f; // SCL into Q
    for (int nt = 0; nt < 4; ++nt) {
      float4 bv4 = *(const float4*)&bias[nh + nt * 16 + quad * 4];
      for (int mt = 0; mt < 4; ++mt) {
        int m_l = wm + mt * 16 + l15;
        int t = (m0 + m_l) & 2047;
        float4 cs = *(const float4*)&rope[t * 32 + nt * 8 + quad * 2];
        float v0 = acc[nt][mt][0] + bv4.x;
        float v1 = acc[nt][mt][1] + bv4.y;
        float v2 = acc[nt][mt][2] + bv4.z;
        float v3 = acc[nt][mt][3] + bv4.w;
        float r0 = fmaf(-v1, cs.y, v0 * cs.x) * qsc;
        float r1 = fmaf( v0, cs.y, v1 * cs.x) * qsc;
        float r2 = fmaf(-v3, cs.w, v2 * cs.z) * qsc;
        float r3 = fmaf( v2, cs.w, v3 * cs.z) * qsc;
        uint2 pv; pv.x = pk2(r0, r1); pv.y = pk2(r2, r3);
        *(uint2*)&Eh[m_l * 72 + nt * 16 + quad * 4] = pv;
      }
    }
  } else {
    // V: transposed [c][m] stride 136; c = nt*16+quad*4+r varies with r
    for (int nt = 0; nt < 4; ++nt) {
      float4 bv4 = *(const float4*)&bias[nh + nt * 16 + quad * 4];
      for (int mt = 0; mt < 4; ++mt) {
        int m_l = wm + mt * 16 + l15;
        int cb = nt * 16 + quad * 4;
        Eh[(cb + 0) * 136 + m_l] = f2bf(acc[nt][mt][0] + bv4.x);
        Eh[(cb + 1) * 136 + m_l] = f2bf(acc[nt][mt][1] + bv4.y);
        Eh[(cb + 2) * 136 + m_l] = f2bf(acc[nt][mt][2] + bv4.z);
        Eh[(cb + 3) * 136 + m_l] = f2bf(acc[nt][mt][3] + bv4.w);
      }
    }
  }
  __syncthreads();

  // ---- coalesced write-out: 16 B per lane
  const int bb = m0 >> 11, t0 = m0 & 2047;
  for (int hf = 0; hf < 2; ++hf) {
    const int nhf = n0 + hf * 64;
    const int hh = nhf / 192;
    const int reg = (nhf % 192) >> 6;
    const u16* Ef = smem + hf * 9216;
    if (reg < 2) {
      u16* dst = (reg == 0 ? Qg : Kg) +
                 ((size_t)(bb * 16 + hh) * 2048 + t0) * 64;
      int chunk = tid & 7, row0 = tid >> 3;
      for (int p = 0; p < 4; ++p) {
        int row = row0 + p * 32;
        u16x8 val = *(const u16x8*)&Ef[row * 72 + chunk * 8];
        *(u16x8*)(dst + (size_t)row * 64 + chunk * 8) = val;
      }
    } else {
      u16* dstv = Vt + (size_t)(bb * 16 + hh) * 64 * 2048 + t0;
      int mch = tid & 15, c0r = tid >> 4;
      for (int p = 0; p < 4; ++p) {
        int c = c0r + p * 16;
        u16x8 val = *(const u16x8*)&Ef[c * 136 + mch * 8];
        *(u16x8*)(dstv + (size_t)c * 2048 + mch * 8) = val;
      }
    }
  }
}

// ------------------- flash attention (causal) -------------------
// BARRIER-FREE ROUND: K/V are NOT staged in LDS (per-head KV = 512 KB is
// L2-resident with XCD affinity; staging + per-iter __syncthreads was the
// coupling that pinned 3 prior rounds at ~1580 cy/tile-iter). Each wave owns
// a 16-row q-subtile HALF-RANGE of KV blocks, reads K/V fragments directly
// from global (16 B/lane contiguous), and runs its own softmax. 4096
// independent waves (16 or 17 iters each, uniform), 1024 blocks x 4 waves =
// 4 waves/SIMD. Pair (s,127-s) split into halves h0=[0,c) / h1=[c,nk) (h1
// owns the diagonal); partials merged once per block via LDS f32 buffers +
// a single __syncthreads.
__device__ __forceinline__ float sub_attn(
    const u16* __restrict__ Qh, const u16* __restrict__ Kh,
    const u16* __restrict__ Vh, u16* Psw,
    int su, int lo, int hi, int quad, int l15, int psw, f32x4 (&O)[4]) {
  const f32x4 vzero = {0.f, 0.f, 0.f, 0.f};
  for (int nt = 0; nt < 4; ++nt) O[nt] = vzero;
  float lsum = 0.f;
  bf16x8 aq[2];
  {
    const u16* qp = Qh + (size_t)(su * 16 + l15) * 64 + quad * 8;
    aq[0] = *(const bf16x8*)(qp);
    aq[1] = *(const bf16x8*)(qp + 32);
  }
  const int nkm1 = su >> 2;           // diagonal kb index
  const int tq = su * 16 + l15;       // this lane's q row
  for (int kb = lo; kb < hi; ++kb) {
    const int k0 = kb * 64;
    // K fragments direct from global: row k0+nt*16+l15, hs ks*32+quad*8
    bf16x8 ak[4][2];
    {
      const u16* kp = Kh + (size_t)(k0 + l15) * 64 + quad * 8;
      for (int nt = 0; nt < 4; ++nt)
        for (int ks = 0; ks < 2; ++ks)
          ak[nt][ks] = *(const bf16x8*)(kp + nt * 1024 + ks * 32);
    }
    f32x4 st[4];
    for (int nt = 0; nt < 4; ++nt) st[nt] = vzero;
    for (int ks = 0; ks < 2; ++ks)
      for (int nt = 0; nt < 4; ++nt)
        st[nt] = __builtin_amdgcn_mfma_f32_16x16x32_bf16(
            ak[nt][ks], aq[ks], st[nt], 0, 0, 0);

    // V fragments (issued here so L2 latency hides under the exp/pack phase)
    bf16x8 bv[4][2];
    {
      const u16* vp = Vh + (size_t)l15 * 2048 + k0 + quad * 8;
      for (int nt = 0; nt < 4; ++nt)
        for (int ks = 0; ks < 2; ++ks)
          bv[nt][ks] = *(const bf16x8*)(vp + (size_t)nt * 32768 + ks * 32);
    }

    // p = exp2(s) (scale folded into Q); pack 4 k's -> one b64 LDS write
    if (kb < nkm1) {  // fully unmasked
      for (int nt = 0; nt < 4; ++nt) {
        float p0 = __builtin_amdgcn_exp2f(st[nt][0]);
        float p1 = __builtin_amdgcn_exp2f(st[nt][1]);
        float p2 = __builtin_amdgcn_exp2f(st[nt][2]);
        float p3 = __builtin_amdgcn_exp2f(st[nt][3]);
        lsum += (p0 + p1) + (p2 + p3);
        uint2 pv; pv.x = pk2(p0, p1); pv.y = pk2(p2, p3);
        *(uint2*)&Psw[l15 * 64 + ((nt * 4 + quad) ^ psw) * 4] = pv;
      }
    } else {  // kb == nkm1: diagonal block, mask k > q
      const int kbase = k0 + quad * 4;
      for (int nt = 0; nt < 4; ++nt) {
        float p[4];
        for (int r = 0; r < 4; ++r) {
          float pv = __builtin_amdgcn_exp2f(st[nt][r]);
          p[r] = (kbase + nt * 16 + r <= tq) ? pv : 0.f;
          lsum += p[r];
        }
        uint2 pv; pv.x = pk2(p[0], p[1]); pv.y = pk2(p[2], p[3]);
        *(uint2*)&Psw[l15 * 64 + ((nt * 4 + quad) ^ psw) * 4] = pv;
      }
    }

    // O += P V  (Psw is wave-private; in-wave LDS ordering suffices)
    for (int ks = 0; ks < 2; ++ks) {
      bf16x8 pa = *(const bf16x8*)&Psw[l15 * 64 + ((ks * 8 + quad * 2) ^ psw) * 4];
      for (int nt = 0; nt < 4; ++nt)
        O[nt] = __builtin_amdgcn_mfma_f32_16x16x32_bf16(
            pa, bv[nt][ks], O[nt], 0, 0, 0);
    }
  }
  // row-sum across the 4 quads: every lane ends with total for q-row l15
  lsum += __shfl_xor(lsum, 16, 64);
  lsum += __shfl_xor(lsum, 32, 64);
  return lsum;
}

__global__ __launch_bounds__(256, 4) void k_attn(
    const u16* __restrict__ Qg, const u16* __restrict__ Kg,
    const u16* __restrict__ Vt, u16* __restrict__ Og) {  // Og: [4096][1024] bf16
  __shared__ alignas(16) u16 Ps[4][1024];      // per-wave P staging (2 KB each)
  __shared__ alignas(16) float MO[4][1024];    // per-wave partial-O stash
  __shared__ float ML[4][16];                  // per-wave partial-l stash
  const int tid = threadIdx.x, lane = tid & 63, w = tid >> 6;  // w in 0..3
  const int quad = lane >> 4, l15 = lane & 15;
  const int id = blockIdx.x;
  const int xcd = id & 7, g = id >> 3;         // g in 0..127
  const int bh = (g >> 5) * 8 + xcd;           // all blocks of a bh on one XCD
  const int gg = g & 31;                       // pair-block within bh
  // wave w: pair = w>>1 (sA=2gg, sB=2gg+1), half = w&1
  const int sp = 2 * gg + (w >> 1);
  const int s1 = sp, s2 = 127 - sp;
  const int hhf = w & 1;
  const int nk1 = (s1 >> 2) + 1, nk2 = (s2 >> 2) + 1;
  const int c1 = nk1 >> 1, c2 = nk2 >> 1;
  const int lo1 = hhf ? c1 : 0, hi1 = hhf ? nk1 : c1;   // h0: 16 iters total,
  const int lo2 = hhf ? c2 : 0, hi2 = hhf ? nk2 : c2;   // h1: 17 — uniform
  const u16* Qh = Qg + (size_t)bh * 2048 * 64;
  const u16* Kh = Kg + (size_t)bh * 2048 * 64;
  const u16* Vh = Vt + (size_t)bh * 64 * 2048;
  u16* Psw = Ps[w];
  const int psw = (l15 & 7) << 1;

  f32x4 O1[4], O2[4];
  const float ls1 = sub_attn(Qh, Kh, Vh, Psw, s1, lo1, hi1, quad, l15, psw, O1);
  const float ls2 = sub_attn(Qh, Kh, Vh, Psw, s2, lo2, hi2, quad, l15, psw, O2);

  // stash the partial this wave does NOT merge (static array names only)
  if (w & 1) {
    for (int nt = 0; nt < 4; ++nt)
      for (int r = 0; r < 4; ++r)
        MO[w][(quad * 4 + r) * 64 + nt * 16 + l15] = O1[nt][r];
    if (lane < 16) ML[w][l15] = ls1;
  } else {
    for (int nt = 0; nt < 4; ++nt)
      for (int r = 0; r < 4; ++r)
        MO[w][(quad * 4 + r) * 64 + nt * 16 + l15] = O2[nt][r];
    if (lane < 16) ML[w][l15] = ls2;
  }
  __syncthreads();

  // merge own-kept partial with partner's stash; normalize; stage into Psw
  const int sm = (w & 1) ? s2 : s1;
  {
    float lsm = ((w & 1) ? ls2 : ls1) + ML[w ^ 1][l15];
    float inv[4];
    for (int r = 0; r < 4; ++r)
      inv[r] = 1.0f / __shfl(lsm, quad * 4 + r, 16);
    if (w & 1) {
      for (int nt = 0; nt < 4; ++nt)
        for (int r = 0; r < 4; ++r) {
          float o = O2[nt][r] + MO[w ^ 1][(quad * 4 + r) * 64 + nt * 16 + l15];
          int row = quad * 4 + r, col = nt * 16 + l15;
          int up = (col >> 2) ^ ((row & 7) << 1);
          Psw[row * 64 + up * 4 + (col & 3)] = f2bf(o * inv[r]);
        }
    } else {
      for (int nt = 0; nt < 4; ++nt)
        for (int r = 0; r < 4; ++r) {
          float o = O1[nt][r] + MO[w ^ 1][(quad * 4 + r) * 64 + nt * 16 + l15];
          int row = quad * 4 + r, col = nt * 16 + l15;
          int up = (col >> 2) ^ ((row & 7) << 1);
          Psw[row * 64 + up * 4 + (col & 3)] = f2bf(o * inv[r]);
        }
    }
  }

  // wave-level coalesced store: 16 rows x 128 B, 4 lanes/row x 2 passes
  const int bb = bh >> 4, h = bh & 15;
  u16* dst = Og + ((size_t)bb * 2048 + sm * 16) * 1024 + h * 64;
  const int rrow = lane >> 2, ch4 = lane & 3;
  for (int p = 0; p < 2; ++p) {
    int chunk = ch4 + p * 4;
    int up = (chunk * 2) ^ ((rrow & 7) << 1);
    u16x8 val = *(const u16x8*)&Psw[rrow * 64 + up * 4];
    *(u16x8*)(dst + (size_t)rrow * 1024 + chunk * 8) = val;
  }
}

// --------------------- output projection GEMM ---------------------
// BM=64, BN=128, BK=64, swizzled staging. grid (8, 64) = 512 blocks (2/CU).
__global__ __launch_bounds__(256, 4) void k_proj(
    const u16* __restrict__ Ag,      // [4096][1024] bf16
    const u16* __restrict__ Wt,      // [1024][1024] bf16 (W_proj^T)
    const float* __restrict__ bias,  // [1024]
    float* __restrict__ out) {       // [4096][1024] f32
  __shared__ alignas(16) u16 As[64 * 64];
  __shared__ alignas(16) u16 Bs[128 * 64];
  const int tid = threadIdx.x;
  const int lane = tid & 63, w = tid >> 6;
  const int quad = lane >> 4, l15 = lane & 15;
  const int m0 = blockIdx.y * 64, n0 = blockIdx.x * 128;
  const int wm = (w & 1) * 32, wn = (w >> 1) * 64;
  const int srow = lane >> 3, sj = lane & 7;
  const int sw = (sj ^ srow) * 8;
  const f32x4 vzero = {0.f, 0.f, 0.f, 0.f};

  f32x4 acc[2][4];
  for (int i = 0; i < 2; ++i)
    for (int j = 0; j < 4; ++j) acc[i][j] = vzero;

  for (int kt = 0; kt < 1024; kt += 64) {
    __syncthreads();
    for (int i = 0; i < 2; ++i) {
      int row = w * 16 + i * 8;
      gld16(Ag + (size_t)(m0 + row + srow) * 1024 + kt + sw, &As[row * 64]);
    }
    for (int i = 0; i < 4; ++i) {
      int row = w * 32 + i * 8;
      gld16(Wt + (size_t)(n0 + row + srow) * 1024 + kt + sw, &Bs[row * 64]);
    }
    __syncthreads();
    for (int ks = 0; ks < 2; ++ks) {
      const int cc = ((ks * 4 + quad) ^ (l15 & 7)) * 8;
      bf16x8 a[2], b[4];
      for (int mt = 0; mt < 2; ++mt)
        a[mt] = *(const bf16x8*)&As[(wm + mt * 16 + l15) * 64 + cc];
      for (int nt = 0; nt < 4; ++nt)
        b[nt] = *(const bf16x8*)&Bs[(wn + nt * 16 + l15) * 64 + cc];
      for (int mt = 0; mt < 2; ++mt)
        for (int nt = 0; nt < 4; ++nt)
          acc[mt][nt] = __builtin_amdgcn_mfma_f32_16x16x32_bf16(
              a[mt], b[nt], acc[mt][nt], 0, 0, 0);
    }
  }

  for (int nt = 0; nt < 4; ++nt) {
    int n = n0 + wn + nt * 16 + l15;
    float bv = bias[n];
    for (int mt = 0; mt < 2; ++mt)
      for (int r = 0; r < 4; ++r) {
        int m = m0 + wm + mt * 16 + quad * 4 + r;
        out[(size_t)m * 1024 + n] = acc[mt][nt][r] + bv;
      }
  }
}

extern "C" void kernel_launch(void* const* d_in, const int* in_sizes, int n_in,
                              void* d_out, int out_size, void* d_ws, size_t ws_size,
                              hipStream_t stream) {
  (void)in_sizes; (void)n_in; (void)out_size; (void)ws_size;
  const float* x     = (const float*)d_in[0];
  const float* Wqkv  = (const float*)d_in[1];
  const float* bqkv  = (const float*)d_in[2];
  const float* Wproj = (const float*)d_in[3];
  const float* bproj = (const float*)d_in[4];
  float* out = (float*)d_out;

  char* ws = (char*)d_ws;
  size_t off = 0;
  u16* Xb    = (u16*)(ws + off); off += (size_t)4096 * 1024 * 2;   // x bf16
  u16* Wqkvt = (u16*)(ws + off); off += (size_t)3072 * 1024 * 2;   // W_qkv^T bf16
  u16* Wpt   = (u16*)(ws + off); off += (size_t)1024 * 1024 * 2;   // W_proj^T bf16
  u16* Qg    = (u16*)(ws + off); off += (size_t)2 * 16 * 2048 * 64 * 2;
  u16* Kg    = (u16*)(ws + off); off += (size_t)2 * 16 * 2048 * 64 * 2;
  u16* Vt    = (u16*)(ws + off); off += (size_t)2 * 16 * 64 * 2048 * 2;
  u16* Att   = (u16*)(ws + off); off += (size_t)4096 * 1024 * 2;
  float2* rope = (float2*)(ws + off); off += (size_t)2048 * 32 * sizeof(float2);

  k_prep<<<8448, 256, 0, stream>>>(x, Xb, Wqkv, Wqkvt, Wproj, Wpt, rope);
  k_qkv<<<dim3(24, 32), 256, 0, stream>>>(Xb, Wqkvt, bqkv, rope, Qg, Kg, Vt);
  k_attn<<<1024, 256, 0, stream>>>(Qg, Kg, Vt, Att);
  k_proj<<<dim3(8, 64), 256, 0, stream>>>(Att, Wpt, bproj, out);
}

// Round 5
// 171.149 us; speedup vs baseline: 1.4750x; 1.4750x over previous
//
#include <hip/hip_runtime.h>

// Problem constants: B=2, T=2048, C=1024, H=16, HS=64
typedef unsigned short u16;
typedef unsigned int u32;
typedef __bf16 bf16x8 __attribute__((ext_vector_type(8)));
typedef float f32x4 __attribute__((ext_vector_type(4)));
typedef u16 u16x4 __attribute__((ext_vector_type(4)));
typedef u16 u16x8 __attribute__((ext_vector_type(8)));

__device__ __forceinline__ u16 f2bf(float f) {
  u32 u = __builtin_bit_cast(u32, f);
  u += 0x7fffu + ((u >> 16) & 1u);   // round-to-nearest-even
  return (u16)(u >> 16);
}

// pack two f32 -> two bf16 (round-half-up) in one u32; a in low half.
__device__ __forceinline__ u32 pk2(float a, float b) {
  u32 ua = __builtin_bit_cast(u32, a) + 0x8000u;
  u32 ub = __builtin_bit_cast(u32, b) + 0x8000u;
  return __builtin_amdgcn_perm(ub, ua, 0x07060302);  // {ub.hi16, ua.hi16}
}

__device__ __forceinline__ void gld16(const void* g, void* l) {
  __builtin_amdgcn_global_load_lds(
      (const __attribute__((address_space(1))) void*)g,
      (__attribute__((address_space(3))) void*)l, 16, 0, 0);
}

// ---------------- merged prep kernel (one launch) ----------------
__global__ __launch_bounds__(256) void k_prep(
    const float* __restrict__ x, u16* __restrict__ xb,
    const float* __restrict__ Wqkv, u16* __restrict__ Wqkvt,
    const float* __restrict__ Wproj, u16* __restrict__ Wpt,
    float2* __restrict__ rope) {
  __shared__ float tile[32][33];
  const int tid = threadIdx.x;
  int bx = blockIdx.x;
  if (bx < 4096) {
    int i = (bx * 256 + tid) * 4;
    float4 v = *(const float4*)(x + i);
    u16x4 o = { f2bf(v.x), f2bf(v.y), f2bf(v.z), f2bf(v.w) };
    *(u16x4*)(xb + i) = o;
    return;
  }
  bx -= 4096;
  const float* src; u16* dst; int R, Cc, bxx, byy;
  if (bx < 3072) {
    src = Wqkv; dst = Wqkvt; R = 1024; Cc = 3072; bxx = bx % 96; byy = bx / 96;
  } else if (bx < 4096) {
    int b = bx - 3072;
    src = Wproj; dst = Wpt; R = 1024; Cc = 1024; bxx = b % 32; byy = b / 32;
  } else {
    int i = (bx - 4096) * 256 + tid;  // 0..65535
    int t = i >> 5, d = i & 31;
    float theta = expf(-(float)d * 0.28782313662425575f);  // ln(10000)/32
    float ang = (float)t * theta;
    rope[i] = make_float2(cosf(ang), sinf(ang));
    return;
  }
  int xx = tid & 31, yy = tid >> 5;
  int c0 = bxx * 32, r0 = byy * 32;
  for (int i = 0; i < 4; ++i)
    tile[yy + 8 * i][xx] = src[(size_t)(r0 + yy + 8 * i) * Cc + c0 + xx];
  __syncthreads();
  for (int i = 0; i < 4; ++i)
    dst[(size_t)(c0 + yy + 8 * i) * R + r0 + xx] = f2bf(tile[xx][yy + 8 * i]);
}

// --------------- QKV GEMM + bias + RoPE + scatter ---------------
// Q is pre-scaled by 1/sqrt(HS)*log2(e) here so k_attn's softmax is a bare
// exp2 of the MFMA output.
__global__ __launch_bounds__(256, 4) void k_qkv(
    const u16* __restrict__ Xb,      // [4096][1024] bf16
    const u16* __restrict__ Wt,      // [3072][1024] bf16 (W_qkv^T)
    const float* __restrict__ bias,  // [3072]
    const float2* __restrict__ rope, // [2048][32]
    u16* __restrict__ Qg,            // [B,H,T,HS]  (scaled)
    u16* __restrict__ Kg,            // [B,H,T,HS]
    u16* __restrict__ Vt) {          // [B,H,HS,T]
  __shared__ alignas(16) u16 smem[18432];  // 36 KB: As|Bs in K-loop, Es after
  u16* As = smem;           // [128][64]
  u16* Bs = smem + 8192;    // [128][64]
  const int tid = threadIdx.x;
  const int lane = tid & 63, w = tid >> 6;
  const int quad = lane >> 4, l15 = lane & 15;
  const int m0 = blockIdx.y * 128, n0 = blockIdx.x * 128;
  const int wm = (w & 1) * 64, wn = (w >> 1) * 64;
  const int srow = lane >> 3, sj = lane & 7;
  const int sw = (sj ^ srow) * 8;   // swizzled source u16 offset
  const f32x4 vzero = {0.f, 0.f, 0.f, 0.f};

  f32x4 acc[4][4];  // [nt][mt] (swapped order)
  for (int i = 0; i < 4; ++i)
    for (int j = 0; j < 4; ++j) acc[i][j] = vzero;

  for (int kt = 0; kt < 1024; kt += 64) {
    __syncthreads();
    for (int i = 0; i < 4; ++i) {
      int row = w * 32 + i * 8;
      gld16(Xb + (size_t)(m0 + row + srow) * 1024 + kt + sw, &As[row * 64]);
      gld16(Wt + (size_t)(n0 + row + srow) * 1024 + kt + sw, &Bs[row * 64]);
    }
    __syncthreads();
    for (int ks = 0; ks < 2; ++ks) {
      const int cc = ((ks * 4 + quad) ^ (l15 & 7)) * 8;
      bf16x8 a[4], b[4];
      for (int mt = 0; mt < 4; ++mt)
        a[mt] = *(const bf16x8*)&As[(wm + mt * 16 + l15) * 64 + cc];
      for (int nt = 0; nt < 4; ++nt)
        b[nt] = *(const bf16x8*)&Bs[(wn + nt * 16 + l15) * 64 + cc];
      for (int nt = 0; nt < 4; ++nt)
        for (int mt = 0; mt < 4; ++mt)
          acc[nt][mt] = __builtin_amdgcn_mfma_f32_16x16x32_bf16(
              b[nt], a[mt], acc[nt][mt], 0, 0, 0);
    }
  }
  __syncthreads();  // all waves done reading As/Bs; safe to overwrite with Es

  // ---- stage into LDS (bias + RoPE applied), wave-uniform region per half
  const int half = w >> 1;
  const int nh = n0 + half * 64;             // 64-aligned -> single region
  const int region = (nh % 192) >> 6;        // 0=Q 1=K 2=V
  u16* Eh = smem + half * 9216;
  if (region < 2) {
    const float qsc = (region == 0) ? 0.18033688011112042f : 1.0f; // SCL into Q
    for (int nt = 0; nt < 4; ++nt) {
      float4 bv4 = *(const float4*)&bias[nh + nt * 16 + quad * 4];
      for (int mt = 0; mt < 4; ++mt) {
        int m_l = wm + mt * 16 + l15;
        int t = (m0 + m_l) & 2047;
        float4 cs = *(const float4*)&rope[t * 32 + nt * 8 + quad * 2];
        float v0 = acc[nt][mt][0] + bv4.x;
        float v1 = acc[nt][mt][1] + bv4.y;
        float v2 = acc[nt][mt][2] + bv4.z;
        float v3 = acc[nt][mt][3] + bv4.w;
        float r0 = fmaf(-v1, cs.y, v0 * cs.x) * qsc;
        float r1 = fmaf( v0, cs.y, v1 * cs.x) * qsc;
        float r2 = fmaf(-v3, cs.w, v2 * cs.z) * qsc;
        float r3 = fmaf( v2, cs.w, v3 * cs.z) * qsc;
        uint2 pv; pv.x = pk2(r0, r1); pv.y = pk2(r2, r3);
        *(uint2*)&Eh[m_l * 72 + nt * 16 + quad * 4] = pv;
      }
    }
  } else {
    // V: transposed [c][m] stride 136; c = nt*16+quad*4+r varies with r
    for (int nt = 0; nt < 4; ++nt) {
      float4 bv4 = *(const float4*)&bias[nh + nt * 16 + quad * 4];
      for (int mt = 0; mt < 4; ++mt) {
        int m_l = wm + mt * 16 + l15;
        int cb = nt * 16 + quad * 4;
        Eh[(cb + 0) * 136 + m_l] = f2bf(acc[nt][mt][0] + bv4.x);
        Eh[(cb + 1) * 136 + m_l] = f2bf(acc[nt][mt][1] + bv4.y);
        Eh[(cb + 2) * 136 + m_l] = f2bf(acc[nt][mt][2] + bv4.z);
        Eh[(cb + 3) * 136 + m_l] = f2bf(acc[nt][mt][3] + bv4.w);
      }
    }
  }
  __syncthreads();

  // ---- coalesced write-out: 16 B per lane
  const int bb = m0 >> 11, t0 = m0 & 2047;
  for (int hf = 0; hf < 2; ++hf) {
    const int nhf = n0 + hf * 64;
    const int hh = nhf / 192;
    const int reg = (nhf % 192) >> 6;
    const u16* Ef = smem + hf * 9216;
    if (reg < 2) {
      u16* dst = (reg == 0 ? Qg : Kg) +
                 ((size_t)(bb * 16 + hh) * 2048 + t0) * 64;
      int chunk = tid & 7, row0 = tid >> 3;
      for (int p = 0; p < 4; ++p) {
        int row = row0 + p * 32;
        u16x8 val = *(const u16x8*)&Ef[row * 72 + chunk * 8];
        *(u16x8*)(dst + (size_t)row * 64 + chunk * 8) = val;
      }
    } else {
      u16* dstv = Vt + (size_t)(bb * 16 + hh) * 64 * 2048 + t0;
      int mch = tid & 15, c0r = tid >> 4;
      for (int p = 0; p < 4; ++p) {
        int c = c0r + p * 16;
        u16x8 val = *(const u16x8*)&Ef[c * 136 + mch * 8];
        *(u16x8*)(dstv + (size_t)c * 2048 + mch * 8) = val;
      }
    }
  }
}

// ------------------- flash attention (causal) -------------------
// COUNTED-VMCNT ROUND: Round-0 structure (512 blocks, uniform 33 KV-iters,
// q-tiles {bx, 31-bx}, dbuf LDS K/V) but the per-iter __syncthreads (which
// drains vmcnt(0) and stalls the global_load_lds prefetch queue — the stall
// that pinned rounds 0-3 at ~1600 cy/iter) is replaced by raw s_barrier +
// counted s_waitcnt vmcnt(4): the next buffer's 4 loads stay in flight
// across both barriers (T3/T4-lite). Loads for iter i are issued at the end
// of iter i-2 -> ~1.7 iterations to land. vmcnt retires in issue order
// (m135); epilogue-A's global stores only cause harmless over-waits since
// the loads we need are always oldest. Last iter (32) uses vmcnt(0).
__global__ __launch_bounds__(256, 4) void k_attn(
    const u16* __restrict__ Qg, const u16* __restrict__ Kg,
    const u16* __restrict__ Vt, u16* __restrict__ Og) {  // Og: [4096][1024] bf16
  __shared__ alignas(16) u16 Ks[2][64 * 64];
  __shared__ alignas(16) u16 Vs[2][64 * 64];   // [hs][kk]
  __shared__ alignas(16) u16 Ps[64 * 64];      // swizzled, stride 64
  const int tid = threadIdx.x, lane = tid & 63, w = tid >> 6;  // w in 0..3
  const int quad = lane >> 4, l15 = lane & 15;
  // id = (bh%8) + 8*((bh/8)*16 + bx)  =>  decode:
  const int id = blockIdx.x;
  const int xr = id & 7, j = id >> 3;
  const int bx = j & 15;
  const int bh = (j >> 4) * 8 + xr;
  const u16* Qh = Qg + (size_t)bh * 2048 * 64;
  const u16* Kh = Kg + (size_t)bh * 2048 * 64;
  const u16* Vh = Vt + (size_t)bh * 64 * 2048;
  const f32x4 vzero = {0.f, 0.f, 0.f, 0.f};
  const int myrow = w * 16;
  const int bb = bh >> 4, h = bh & 15;

  const int qA = bx, qB = 31 - bx;
  const int nkA = qA + 1;            // iters for tile A; total = 33 always
  const int q0A = qA * 64, q0B = qB * 64;

  // staging source swizzle: lane (r8,j8) fetches global chunk j8^r8 of its row
  const int r8 = lane >> 3, j8 = lane & 7;
  const int sw_c = (j8 ^ r8) * 8;
  const int psw = (l15 & 7) << 1;    // Ps unit swizzle for this lane's P-row
  const int prow = myrow + l15;

  // Q fragments for BOTH tiles, loaded before any staging so they are the
  // oldest vmem ops (retire under the first counted wait).
  bf16x8 aqA[2], aqB[2];
  {
    const u16* qpA = Qh + (size_t)(q0A + prow) * 64 + quad * 8;
    aqA[0] = *(const bf16x8*)(qpA);
    aqA[1] = *(const bf16x8*)(qpA + 32);
    const u16* qpB = Qh + (size_t)(q0B + prow) * 64 + quad * 8;
    aqB[0] = *(const bf16x8*)(qpB);
    aqB[1] = *(const bf16x8*)(qpB + 32);
  }
  asm volatile("" ::: "memory");  // pin aq loads before staging issue order

  // linear KV-block index i (0..32) -> k0 of the block it stages
  auto stage = [&](int i, int b) {
    const int kk0 = (i < nkA ? i : i - nkA) * 64;
    for (int t = 0; t < 2; ++t) {
      int row = w * 16 + t * 8;
      gld16(Kh + (size_t)(kk0 + row + r8) * 64 + sw_c, &Ks[b][row * 64]);
      gld16(Vh + (size_t)(row + r8) * 2048 + kk0 + sw_c, &Vs[b][row * 64]);
    }
  };
  stage(0, 0);
  stage(1, 1);

  float lsum = 0.f;
  f32x4 O[4];
  for (int nt = 0; nt < 4; ++nt) O[nt] = vzero;

  for (int it = 0; it < 33; ++it) {
    const int buf = it & 1;
    // wait for THIS buffer's 4 loads; leave the other buffer's 4 in flight
    if (it == 32) asm volatile("s_waitcnt vmcnt(0)" ::: "memory");
    else          asm volatile("s_waitcnt vmcnt(4)" ::: "memory");
    asm volatile("s_barrier" ::: "memory");   // staged buf visible to all

    const bool isA = it < nkA;
    const int kb = isA ? it : it - nkA;
    const int k0 = kb * 64;
    const int qt = isA ? qA : qB;
    const int q0 = isA ? q0A : q0B;
    const bf16x8 q0f = isA ? aqA[0] : aqB[0];
    const bf16x8 q1f = isA ? aqA[1] : aqB[1];

    // S^T = K Q^T : rows = k (64), cols = q (this wave's 16)
    f32x4 st[4];
    for (int nt = 0; nt < 4; ++nt) st[nt] = vzero;
    for (int ks = 0; ks < 2; ++ks) {
      const bf16x8 qf = ks ? q1f : q0f;
      bf16x8 ak[4];
      for (int nt = 0; nt < 4; ++nt)
        ak[nt] = *(const bf16x8*)&Ks[buf][(nt * 16 + l15) * 64 +
                                         ((ks * 4 + quad) ^ (l15 & 7)) * 8];
      for (int nt = 0; nt < 4; ++nt)
        st[nt] = __builtin_amdgcn_mfma_f32_16x16x32_bf16(ak[nt], qf, st[nt], 0, 0, 0);
    }

    // p = exp2(s) (scale pre-folded into Q); pack 4 k's -> one b64 write
    if (kb < qt) {  // fully unmasked block
      for (int nt = 0; nt < 4; ++nt) {
        float p0 = __builtin_amdgcn_exp2f(st[nt][0]);
        float p1 = __builtin_amdgcn_exp2f(st[nt][1]);
        float p2 = __builtin_amdgcn_exp2f(st[nt][2]);
        float p3 = __builtin_amdgcn_exp2f(st[nt][3]);
        lsum += (p0 + p1) + (p2 + p3);
        uint2 pv; pv.x = pk2(p0, p1); pv.y = pk2(p2, p3);
        *(uint2*)&Ps[prow * 64 + ((nt * 4 + quad) ^ psw) * 4] = pv;
      }
    } else {  // diagonal block: mask k > tq
      const int tq = q0 + prow;
      const int kbase = k0 + quad * 4;
      for (int nt = 0; nt < 4; ++nt) {
        float p[4];
        for (int r = 0; r < 4; ++r) {
          float pv = __builtin_amdgcn_exp2f(st[nt][r]);
          p[r] = (kbase + nt * 16 + r <= tq) ? pv : 0.f;
          lsum += p[r];
        }
        uint2 pv; pv.x = pk2(p[0], p[1]); pv.y = pk2(p[2], p[3]);
        *(uint2*)&Ps[prow * 64 + ((nt * 4 + quad) ^ psw) * 4] = pv;
      }
    }

    // O += P V  (Ps rows are wave-private; in-wave LDS order suffices)
    for (int ks = 0; ks < 2; ++ks) {
      bf16x8 a = *(const bf16x8*)&Ps[prow * 64 + ((ks * 8 + quad * 2) ^ psw) * 4];
      bf16x8 bv[4];
      for (int nt = 0; nt < 4; ++nt)
        bv[nt] = *(const bf16x8*)&Vs[buf][(nt * 16 + l15) * 64 +
                                         ((ks * 4 + quad) ^ (l15 & 7)) * 8];
      for (int nt = 0; nt < 4; ++nt)
        O[nt] = __builtin_amdgcn_mfma_f32_16x16x32_bf16(a, bv[nt], O[nt], 0, 0, 0);
    }

    // all waves done reading buf -> safe to re-stage it with block it+2
    asm volatile("s_barrier" ::: "memory");
    if (it + 2 < 33) stage(it + 2, buf);

    // ---- tile-A epilogue (mid-stream, block-uniform), overlaps staging
    if (it == nkA - 1) {
      float ls = lsum;
      ls += __shfl_xor(ls, 16, 64);
      ls += __shfl_xor(ls, 32, 64);
      float inv[4];
      for (int r = 0; r < 4; ++r)
        inv[r] = 1.0f / __shfl(ls, quad * 4 + r, 16);
      for (int nt = 0; nt < 4; ++nt)
        for (int r = 0; r < 4; ++r) {
          int row = myrow + quad * 4 + r;
          int col = nt * 16 + l15;
          int up = (col >> 2) ^ ((row & 7) << 1);
          Ps[row * 64 + up * 4 + (col & 3)] = f2bf(O[nt][r] * inv[r]);
        }
      asm volatile("s_waitcnt lgkmcnt(0)" ::: "memory");
      asm volatile("s_barrier" ::: "memory");
      u16* dst = Og + ((size_t)bb * 2048 + q0A) * 1024 + h * 64;
      int chunk = tid & 7, row0 = tid >> 3;   // 32 rows x 8 chunks
      for (int p = 0; p < 2; ++p) {
        int row = row0 + p * 32;
        int up = (chunk * 2) ^ ((row & 7) << 1);
        u16x8 val = *(const u16x8*)&Ps[row * 64 + up * 4];
        *(u16x8*)(dst + (size_t)row * 1024 + chunk * 8) = val;
      }
      // reset accumulators for tile B
      lsum = 0.f;
      for (int nt = 0; nt < 4; ++nt) O[nt] = vzero;
      // next iteration's top barrier protects Ps reuse (its ds_reads were
      // forced complete by the store's data dependency before arrival)
    }
  }

  // ---- tile-B epilogue
  float ls = lsum;
  ls += __shfl_xor(ls, 16, 64);
  ls += __shfl_xor(ls, 32, 64);
  float inv[4];
  for (int r = 0; r < 4; ++r)
    inv[r] = 1.0f / __shfl(ls, quad * 4 + r, 16);
  for (int nt = 0; nt < 4; ++nt)
    for (int r = 0; r < 4; ++r) {
      int row = myrow + quad * 4 + r;
      int col = nt * 16 + l15;
      int up = (col >> 2) ^ ((row & 7) << 1);
      Ps[row * 64 + up * 4 + (col & 3)] = f2bf(O[nt][r] * inv[r]);
    }
  asm volatile("s_waitcnt lgkmcnt(0)" ::: "memory");
  asm volatile("s_barrier" ::: "memory");
  u16* dst = Og + ((size_t)bb * 2048 + q0B) * 1024 + h * 64;
  int chunk = tid & 7, row0 = tid >> 3;   // 32 rows x 8 chunks
  for (int p = 0; p < 2; ++p) {
    int row = row0 + p * 32;
    int up = (chunk * 2) ^ ((row & 7) << 1);
    u16x8 val = *(const u16x8*)&Ps[row * 64 + up * 4];
    *(u16x8*)(dst + (size_t)row * 1024 + chunk * 8) = val;
  }
}

// --------------------- output projection GEMM ---------------------
// BM=64, BN=128, BK=64, swizzled staging. grid (8, 64) = 512 blocks (2/CU).
__global__ __launch_bounds__(256, 4) void k_proj(
    const u16* __restrict__ Ag,      // [4096][1024] bf16
    const u16* __restrict__ Wt,      // [1024][1024] bf16 (W_proj^T)
    const float* __restrict__ bias,  // [1024]
    float* __restrict__ out) {       // [4096][1024] f32
  __shared__ alignas(16) u16 As[64 * 64];
  __shared__ alignas(16) u16 Bs[128 * 64];
  const int tid = threadIdx.x;
  const int lane = tid & 63, w = tid >> 6;
  const int quad = lane >> 4, l15 = lane & 15;
  const int m0 = blockIdx.y * 64, n0 = blockIdx.x * 128;
  const int wm = (w & 1) * 32, wn = (w >> 1) * 64;
  const int srow = lane >> 3, sj = lane & 7;
  const int sw = (sj ^ srow) * 8;
  const f32x4 vzero = {0.f, 0.f, 0.f, 0.f};

  f32x4 acc[2][4];
  for (int i = 0; i < 2; ++i)
    for (int j = 0; j < 4; ++j) acc[i][j] = vzero;

  for (int kt = 0; kt < 1024; kt += 64) {
    __syncthreads();
    for (int i = 0; i < 2; ++i) {
      int row = w * 16 + i * 8;
      gld16(Ag + (size_t)(m0 + row + srow) * 1024 + kt + sw, &As[row * 64]);
    }
    for (int i = 0; i < 4; ++i) {
      int row = w * 32 + i * 8;
      gld16(Wt + (size_t)(n0 + row + srow) * 1024 + kt + sw, &Bs[row * 64]);
    }
    __syncthreads();
    for (int ks = 0; ks < 2; ++ks) {
      const int cc = ((ks * 4 + quad) ^ (l15 & 7)) * 8;
      bf16x8 a[2], b[4];
      for (int mt = 0; mt < 2; ++mt)
        a[mt] = *(const bf16x8*)&As[(wm + mt * 16 + l15) * 64 + cc];
      for (int nt = 0; nt < 4; ++nt)
        b[nt] = *(const bf16x8*)&Bs[(wn + nt * 16 + l15) * 64 + cc];
      for (int mt = 0; mt < 2; ++mt)
        for (int nt = 0; nt < 4; ++nt)
          acc[mt][nt] = __builtin_amdgcn_mfma_f32_16x16x32_bf16(
              a[mt], b[nt], acc[mt][nt], 0, 0, 0);
    }
  }

  for (int nt = 0; nt < 4; ++nt) {
    int n = n0 + wn + nt * 16 + l15;
    float bv = bias[n];
    for (int mt = 0; mt < 2; ++mt)
      for (int r = 0; r < 4; ++r) {
        int m = m0 + wm + mt * 16 + quad * 4 + r;
        out[(size_t)m * 1024 + n] = acc[mt][nt][r] + bv;
      }
  }
}

extern "C" void kernel_launch(void* const* d_in, const int* in_sizes, int n_in,
                              void* d_out, int out_size, void* d_ws, size_t ws_size,
                              hipStream_t stream) {
  (void)in_sizes; (void)n_in; (void)out_size; (void)ws_size;
  const float* x     = (const float*)d_in[0];
  const float* Wqkv  = (const float*)d_in[1];
  const float* bqkv  = (const float*)d_in[2];
  const float* Wproj = (const float*)d_in[3];
  const float* bproj = (const float*)d_in[4];
  float* out = (float*)d_out;

  char* ws = (char*)d_ws;
  size_t off = 0;
  u16* Xb    = (u16*)(ws + off); off += (size_t)4096 * 1024 * 2;   // x bf16
  u16* Wqkvt = (u16*)(ws + off); off += (size_t)3072 * 1024 * 2;   // W_qkv^T bf16
  u16* Wpt   = (u16*)(ws + off); off += (size_t)1024 * 1024 * 2;   // W_proj^T bf16
  u16* Qg    = (u16*)(ws + off); off += (size_t)2 * 16 * 2048 * 64 * 2;
  u16* Kg    = (u16*)(ws + off); off += (size_t)2 * 16 * 2048 * 64 * 2;
  u16* Vt    = (u16*)(ws + off); off += (size_t)2 * 16 * 64 * 2048 * 2;
  u16* Att   = (u16*)(ws + off); off += (size_t)4096 * 1024 * 2;
  float2* rope = (float2*)(ws + off); off += (size_t)2048 * 32 * sizeof(float2);

  k_prep<<<8448, 256, 0, stream>>>(x, Xb, Wqkv, Wqkvt, Wproj, Wpt, rope);
  k_qkv<<<dim3(24, 32), 256, 0, stream>>>(Xb, Wqkvt, bqkv, rope, Qg, Kg, Vt);
  k_attn<<<512, 256, 0, stream>>>(Qg, Kg, Vt, Att);
  k_proj<<<dim3(8, 64), 256, 0, stream>>>(Att, Wpt, bproj, out);
}